// Round 1
// baseline (1280.700 us; speedup 1.0000x reference)
//
#include <hip/hip_runtime.h>
#include <hip/hip_bf16.h>
#include <stdint.h>

typedef __bf16 bf16;
typedef __bf16 bf16x8 __attribute__((ext_vector_type(8)));
typedef __bf16 bf16x4 __attribute__((ext_vector_type(4)));
typedef float  floatx4 __attribute__((ext_vector_type(4)));
typedef unsigned int uint32;

#define B_  8
#define C_  2048
#define N_  8000
#define H_  256
#define O_  1000
#define OP_ 1024   // O padded to MFMA-friendly 1024

// async global->LDS, 16B per lane; LDS dst = wave-uniform base + lane*16
__device__ __forceinline__ void gll16(const void* g, void* l) {
  __builtin_amdgcn_global_load_lds((const __attribute__((address_space(1))) void*)g,
                                   (__attribute__((address_space(3))) void*)l, 16, 0, 0);
}

// -------------------- weight pre-cast (fp32 -> bf16, W2 padded to 1024 rows) -----
__global__ __launch_bounds__(256) void castw(const float* __restrict__ W0,
                                             const float* __restrict__ W1,
                                             const float* __restrict__ W2,
                                             bf16* __restrict__ W0b,
                                             bf16* __restrict__ W1b,
                                             bf16* __restrict__ W2b) {
  int idx = blockIdx.x * 256 + threadIdx.x;
  if (idx < 524288) {
    W0b[idx] = (bf16)W0[idx];
  } else if (idx < 524288 + 65536) {
    int i = idx - 524288;
    W1b[i] = (bf16)W1[i];
  } else {
    int i = idx - (524288 + 65536);        // < 1024*256
    int o = i >> 8, k = i & 255;
    W2b[i] = (o < O_) ? (bf16)W2[o * 256 + k] : (bf16)0.0f;
  }
}

// -------------------- layer 1: h1T[b][n][h] = clip(relu(W0 x + b0)) + mask -------
// BM=256(=H full) x BN=64 x BK=32, 256 threads (4 waves), 16x16x32 bf16 MFMA.
// x (fp32, n-contiguous) is transposed+cast into LDS; mask = any(x>0) over C fused.
__global__ __launch_bounds__(256) void gemm1(const float* __restrict__ x,
                                             const bf16* __restrict__ W0b,
                                             const float* __restrict__ bias0,
                                             bf16* __restrict__ h1T,
                                             float* __restrict__ maskb) {
  __shared__ union {
    struct { bf16 A[H_ * 32]; bf16 Bt[64 * 40]; } st;  // A: [m][k] 64B rows (gll); Bt padded stride 40
    bf16 HT[64 * 264];                                  // epilogue transpose [n][m], stride 264
  } sm;
  __shared__ float sbias[256];
  __shared__ uint32 nflag[64];

  const int tid  = threadIdx.x;
  const int wave = tid >> 6, lane = tid & 63;
  const int l16  = lane & 15, l4 = lane >> 4;
  const int n0   = blockIdx.x * 64;
  const int b    = blockIdx.y;

  sbias[tid] = bias0[tid];
  if (tid < 64) nflag[tid] = 0;

  const int kp = tid >> 4;          // 0..15 -> k-pair 2*kp
  const int n4 = (tid & 15) * 4;    // 0..60
  const float* xbase = x + (size_t)b * C_ * N_ + n0 + n4;

  floatx4 acc[4][4];
  #pragma unroll
  for (int i = 0; i < 4; ++i)
    #pragma unroll
    for (int j = 0; j < 4; ++j)
      acc[i][j] = floatx4{0.f, 0.f, 0.f, 0.f};

  uint32 fl = 0;

  for (int k0 = 0; k0 < C_; k0 += 32) {
    // A tile: W0b[m][k0..k0+32), 1024 16B chunks via global_load_lds
    #pragma unroll
    for (int i = 0; i < 4; ++i) {
      int c = i * 256 + tid;
      gll16(W0b + (size_t)(c >> 2) * C_ + k0 + (c & 3) * 8, &sm.st.A[c * 8]);
    }
    // B tile: x[k][n] -> LDS Bt[n][k] (cast fp32->bf16, transpose, k-pair packed b32)
    const float* xr = xbase + (size_t)(k0 + 2 * kp) * N_;
    float4 q0 = *(const float4*)xr;
    float4 q1 = *(const float4*)(xr + N_);
    float a0[4] = {q0.x, q0.y, q0.z, q0.w};
    float a1[4] = {q1.x, q1.y, q1.z, q1.w};
    uint32* bw = (uint32*)sm.st.Bt;
    #pragma unroll
    for (int i = 0; i < 4; ++i) {
      if (a0[i] > 0.f || a1[i] > 0.f) fl |= (1u << i);
      union { bf16 h[2]; uint32 u; } p;
      p.h[0] = (bf16)a0[i];   // k = k0+2kp
      p.h[1] = (bf16)a1[i];   // k = k0+2kp+1
      bw[(n4 + i) * 20 + kp] = p.u;   // row stride 40 elems = 20 uints
    }
    __syncthreads();

    bf16x8 af[4], bfr[4];
    #pragma unroll
    for (int mt = 0; mt < 4; ++mt)
      af[mt] = *(const bf16x8*)&sm.st.A[(wave * 64 + mt * 16 + l16) * 32 + l4 * 8];
    #pragma unroll
    for (int nt = 0; nt < 4; ++nt)
      bfr[nt] = *(const bf16x8*)&sm.st.Bt[(nt * 16 + l16) * 40 + l4 * 8];
    #pragma unroll
    for (int mt = 0; mt < 4; ++mt)
      #pragma unroll
      for (int nt = 0; nt < 4; ++nt)
        acc[mt][nt] = __builtin_amdgcn_mfma_f32_16x16x32_bf16(af[mt], bfr[nt], acc[mt][nt], 0, 0, 0);
    __syncthreads();
  }

  // fused mask: any(x>0) over all C for this block's 64 columns
  #pragma unroll
  for (int i = 0; i < 4; ++i)
    if (fl & (1u << i)) atomicOr(&nflag[n4 + i], 1u);
  __syncthreads();
  if (tid < 64) maskb[(size_t)b * N_ + n0 + tid] = nflag[tid] ? 1.f : 0.f;

  // epilogue: bias + relu + clip -> bf16, LDS transpose to [n][m], coalesced store
  #pragma unroll
  for (int mt = 0; mt < 4; ++mt) {
    int m0 = wave * 64 + mt * 16 + l4 * 4;
    #pragma unroll
    for (int nt = 0; nt < 4; ++nt) {
      int n = nt * 16 + l16;
      bf16x4 hv;
      #pragma unroll
      for (int r = 0; r < 4; ++r) {
        float v = acc[mt][nt][r] + sbias[m0 + r];
        v = fminf(fmaxf(v, 0.f), 1.0e4f);
        hv[r] = (bf16)v;
      }
      *(bf16x4*)&sm.HT[n * 264 + m0] = hv;
    }
  }
  __syncthreads();
  {
    int n = tid >> 2, q = tid & 3;   // 4 threads per n-row, 128B each
    const char* src = (const char*)&sm.HT[n * 264 + q * 64];
    bf16* dst = h1T + ((size_t)b * N_ + n0 + n) * H_ + q * 64;
    #pragma unroll
    for (int j = 0; j < 8; ++j)
      *(uint4*)((char*)dst + j * 16) = *(const uint4*)(src + j * 16);
  }
}

// -------------------- layers 2/3: both operands k-contiguous, full gll staging ---
// OUTL=0: h2T[b][n][m] = clip(relu(W1 h1 + b1));  OUTL=1: y[b][o][n] = W2 h2 + b2
template <int OUTL>
__global__ __launch_bounds__(256) void gemmA(const bf16* __restrict__ A,   // [Mtot][256]
                                             const float* __restrict__ bias, int biasLim,
                                             const bf16* __restrict__ Bt,  // [B][N][256]
                                             bf16* __restrict__ outp) {
  __shared__ union {
    struct { bf16 A[256 * 32]; bf16 Bs[64 * 32]; } st;
    bf16 HT[64 * 264];
    bf16 YT[256 * 72];
  } sm;
  __shared__ float sbias[256];

  const int tid  = threadIdx.x;
  const int wave = tid >> 6, lane = tid & 63;
  const int l16  = lane & 15, l4 = lane >> 4;
  const int n0   = blockIdx.x * 64;
  const int mb   = blockIdx.y;
  const int b    = blockIdx.z;
  const int m0g  = mb * 256;

  { int og = m0g + tid; sbias[tid] = (og < biasLim) ? bias[og] : 0.f; }

  floatx4 acc[4][4];
  #pragma unroll
  for (int i = 0; i < 4; ++i)
    #pragma unroll
    for (int j = 0; j < 4; ++j)
      acc[i][j] = floatx4{0.f, 0.f, 0.f, 0.f};

  const bf16* Bbase = Bt + ((size_t)b * N_ + n0) * 256;

  for (int k0 = 0; k0 < 256; k0 += 32) {
    #pragma unroll
    for (int i = 0; i < 4; ++i) {
      int c = i * 256 + tid;
      gll16(A + (size_t)(m0g + (c >> 2)) * 256 + k0 + (c & 3) * 8, &sm.st.A[c * 8]);
    }
    gll16(Bbase + (size_t)(tid >> 2) * 256 + k0 + (tid & 3) * 8, &sm.st.Bs[tid * 8]);
    __syncthreads();

    bf16x8 af[4], bfr[4];
    #pragma unroll
    for (int mt = 0; mt < 4; ++mt)
      af[mt] = *(const bf16x8*)&sm.st.A[(wave * 64 + mt * 16 + l16) * 32 + l4 * 8];
    #pragma unroll
    for (int nt = 0; nt < 4; ++nt)
      bfr[nt] = *(const bf16x8*)&sm.st.Bs[(nt * 16 + l16) * 32 + l4 * 8];
    #pragma unroll
    for (int mt = 0; mt < 4; ++mt)
      #pragma unroll
      for (int nt = 0; nt < 4; ++nt)
        acc[mt][nt] = __builtin_amdgcn_mfma_f32_16x16x32_bf16(af[mt], bfr[nt], acc[mt][nt], 0, 0, 0);
    __syncthreads();
  }

  if constexpr (!OUTL) {
    #pragma unroll
    for (int mt = 0; mt < 4; ++mt) {
      int m0 = wave * 64 + mt * 16 + l4 * 4;
      #pragma unroll
      for (int nt = 0; nt < 4; ++nt) {
        int n = nt * 16 + l16;
        bf16x4 hv;
        #pragma unroll
        for (int r = 0; r < 4; ++r) {
          float v = acc[mt][nt][r] + sbias[m0 + r];
          v = fminf(fmaxf(v, 0.f), 1.0e4f);
          hv[r] = (bf16)v;
        }
        *(bf16x4*)&sm.HT[n * 264 + m0] = hv;
      }
    }
    __syncthreads();
    int n = tid >> 2, q = tid & 3;
    const char* src = (const char*)&sm.HT[n * 264 + q * 64];
    bf16* dst = outp + ((size_t)b * N_ + n0 + n) * H_ + q * 64;
    #pragma unroll
    for (int j = 0; j < 8; ++j)
      *(uint4*)((char*)dst + j * 16) = *(const uint4*)(src + j * 16);
  } else {
    #pragma unroll
    for (int mt = 0; mt < 4; ++mt) {
      int m0 = wave * 64 + mt * 16 + l4 * 4;
      #pragma unroll
      for (int nt = 0; nt < 4; ++nt) {
        int n = nt * 16 + l16;
        #pragma unroll
        for (int r = 0; r < 4; ++r) {
          float v = acc[mt][nt][r] + sbias[m0 + r];   // no activation on output layer
          sm.YT[(m0 + r) * 72 + n] = (bf16)v;
        }
      }
    }
    __syncthreads();
    // one o-row (64 n, 128B) per thread, coalesced
    bf16* dst = outp + ((size_t)b * OP_ + m0g + tid) * N_ + n0;
    const char* src = (const char*)&sm.YT[tid * 72];
    #pragma unroll
    for (int j = 0; j < 8; ++j)
      *(uint4*)((char*)dst + j * 16) = *(const uint4*)(src + j * 16);
  }
}

// -------------------- top-k prefix averaging ------------------------------------
__device__ __forceinline__ uint32 f2key(float f) {
  uint32 u = __float_as_uint(f);
  return (u & 0x80000000u) ? ~u : (u | 0x80000000u);
}
__device__ __forceinline__ float key2f(uint32 k) {
  uint32 u = (k & 0x80000000u) ? (k & 0x7fffffffu) : ~k;
  return __uint_as_float(u);
}

__global__ __launch_bounds__(256) void topk(const bf16* __restrict__ y,
                                            const float* __restrict__ maskb,
                                            float* __restrict__ out) {
  __shared__ uint32 keys[8192];
  __shared__ uint32 cand[128];
  __shared__ float  m100[128];
  __shared__ int    redw[4];
  __shared__ int    totalS;
  __shared__ int    gcnt;

  const int tid = threadIdx.x;
  const int wave = tid >> 6, lane = tid & 63;
  const int o = blockIdx.x, b = blockIdx.y;

  const bf16* yr = y + ((size_t)b * OP_ + o) * N_;
  const float* mr = maskb + (size_t)b * N_;

  #pragma unroll 4
  for (int i = 0; i < 32; ++i) {
    int n = i * 256 + tid;
    if (n < N_) {
      float v = (float)yr[n] * mr[n];
      keys[n] = f2key(v);
    } else {
      keys[n] = 0u;   // key-min pad
    }
  }
  if (tid < 128) m100[tid] = (tid < 100) ? mr[tid] : 0.f;
  if (tid == 0) gcnt = 0;
  __syncthreads();

  // exact 100th-largest key via 32-bit radix descent
  uint32 prefix = 0;
  for (int bit = 31; bit >= 0; --bit) {
    uint32 candv = prefix | (1u << bit);
    int c = 0;
    #pragma unroll 8
    for (int i = 0; i < 32; ++i)
      c += (keys[i * 256 + tid] >= candv);
    #pragma unroll
    for (int off = 32; off > 0; off >>= 1)
      c += __shfl_down(c, off);
    if (lane == 0) redw[wave] = c;
    __syncthreads();
    if (tid == 0) totalS = redw[0] + redw[1] + redw[2] + redw[3];
    __syncthreads();
    if (totalS >= 100) prefix = candv;
  }

  // gather strictly-greater (count <= 99 guaranteed), fill ties with T
  #pragma unroll 8
  for (int i = 0; i < 32; ++i) {
    uint32 k = keys[i * 256 + tid];
    if (k > prefix) { int p = atomicAdd(&gcnt, 1); cand[p] = k; }
  }
  __syncthreads();
  int cg = gcnt;
  if (tid >= cg && tid < 100) cand[tid] = prefix;
  if (tid >= 100 && tid < 128) cand[tid] = 0u;
  __syncthreads();

  // bitonic sort 128 descending
  for (int k = 2; k <= 128; k <<= 1) {
    for (int j = k >> 1; j > 0; j >>= 1) {
      if (tid < 128) {
        int ixj = tid ^ j;
        if (ixj > tid) {
          uint32 a = cand[tid], bb = cand[ixj];
          bool desc = ((tid & k) == 0);
          if (desc ? (a < bb) : (a > bb)) { cand[tid] = bb; cand[ixj] = a; }
        }
      }
      __syncthreads();
    }
  }

  if (tid == 0) {
    const int KSv[4] = {10, 25, 50, 100};
    float num = 0.f, den = 0.f, pred = 0.f;
    int ki = 0;
    for (int j = 0; j < 100; ++j) {
      float v = key2f(cand[j]);
      float m = m100[j];
      num += v * m;
      den += m;
      if (j + 1 == KSv[ki]) { pred += 0.25f * num / den; ++ki; }
    }
    out[(size_t)b * O_ + o] = pred;
  }
}

// -------------------- launcher ---------------------------------------------------
extern "C" void kernel_launch(void* const* d_in, const int* in_sizes, int n_in,
                              void* d_out, int out_size, void* d_ws, size_t ws_size,
                              hipStream_t stream) {
  const float* x  = (const float*)d_in[0];
  const float* W0 = (const float*)d_in[1];
  const float* b0 = (const float*)d_in[2];
  const float* W1 = (const float*)d_in[3];
  const float* b1 = (const float*)d_in[4];
  const float* W2 = (const float*)d_in[5];
  const float* b2 = (const float*)d_in[6];
  float* out = (float*)d_out;

  char* ws = (char*)d_ws;
  // workspace layout (bytes), total ~198.6 MB
  bf16*  W0b  = (bf16*)(ws + 0);                    // 1,048,576
  bf16*  W1b  = (bf16*)(ws + 1048576);              //   131,072
  bf16*  W2b  = (bf16*)(ws + 1179648);              //   524,288 (1024 rows)
  float* mk   = (float*)(ws + 1703936);             //   256,000
  bf16*  h1T  = (bf16*)(ws + 1959936);              // 32,768,000
  bf16*  h2T  = (bf16*)(ws + 34727936);             // 32,768,000
  bf16*  yb   = (bf16*)(ws + 67495936);             // 131,072,000  -> end 198,567,936

  castw<<<3328, 256, 0, stream>>>(W0, W1, W2, W0b, W1b, W2b);
  gemm1<<<dim3(125, 8), 256, 0, stream>>>(x, W0b, b0, h1T, mk);
  gemmA<0><<<dim3(125, 1, 8), 256, 0, stream>>>(W1b, b1, H_, h1T, h2T);
  gemmA<1><<<dim3(125, 4, 8), 256, 0, stream>>>(W2b, b2, O_, h2T, yb);
  topk<<<dim3(1000, 8), 256, 0, stream>>>(yb, mk, out);
}

// Round 2
// 1008.391 us; speedup vs baseline: 1.2700x; 1.2700x over previous
//
#include <hip/hip_runtime.h>
#include <hip/hip_bf16.h>
#include <stdint.h>

typedef __bf16 bf16;
typedef __bf16 bf16x8 __attribute__((ext_vector_type(8)));
typedef __bf16 bf16x4 __attribute__((ext_vector_type(4)));
typedef float  floatx4 __attribute__((ext_vector_type(4)));
typedef unsigned int uint32;

#define B_  8
#define C_  2048
#define N_  8000
#define H_  256
#define O_  1000
#define OP_ 1024   // O padded to MFMA-friendly 1024

// async global->LDS, 16B per lane; LDS dst = wave-uniform base + lane*16
__device__ __forceinline__ void gll16(const void* g, void* l) {
  __builtin_amdgcn_global_load_lds((const __attribute__((address_space(1))) void*)g,
                                   (__attribute__((address_space(3))) void*)l, 16, 0, 0);
}

// -------------------- weight pre-cast (fp32 -> bf16, W2 padded to 1024 rows) -----
__global__ __launch_bounds__(256) void castw(const float* __restrict__ W0,
                                             const float* __restrict__ W1,
                                             const float* __restrict__ W2,
                                             bf16* __restrict__ W0b,
                                             bf16* __restrict__ W1b,
                                             bf16* __restrict__ W2b) {
  int idx = blockIdx.x * 256 + threadIdx.x;
  if (idx < 524288) {
    W0b[idx] = (bf16)W0[idx];
  } else if (idx < 524288 + 65536) {
    int i = idx - 524288;
    W1b[i] = (bf16)W1[i];
  } else {
    int i = idx - (524288 + 65536);        // < 1024*256
    int o = i >> 8, k = i & 255;
    W2b[i] = (o < O_) ? (bf16)W2[o * 256 + k] : (bf16)0.0f;
  }
}

// -------------------- layer 1: h1T[b][n][h] = clip(relu(W0 x + b0)) + mask -------
__global__ __launch_bounds__(256) void gemm1(const float* __restrict__ x,
                                             const bf16* __restrict__ W0b,
                                             const float* __restrict__ bias0,
                                             bf16* __restrict__ h1T,
                                             float* __restrict__ maskb) {
  __shared__ union {
    struct { bf16 A[H_ * 32]; bf16 Bt[64 * 40]; } st;
    bf16 HT[64 * 264];
  } sm;
  __shared__ float sbias[256];
  __shared__ uint32 nflag[64];

  const int tid  = threadIdx.x;
  const int wave = tid >> 6, lane = tid & 63;
  const int l16  = lane & 15, l4 = lane >> 4;
  const int n0   = blockIdx.x * 64;
  const int b    = blockIdx.y;

  sbias[tid] = bias0[tid];
  if (tid < 64) nflag[tid] = 0;

  const int kp = tid >> 4;          // 0..15 -> k-pair 2*kp
  const int n4 = (tid & 15) * 4;    // 0..60
  const float* xbase = x + (size_t)b * C_ * N_ + n0 + n4;

  floatx4 acc[4][4];
  #pragma unroll
  for (int i = 0; i < 4; ++i)
    #pragma unroll
    for (int j = 0; j < 4; ++j)
      acc[i][j] = floatx4{0.f, 0.f, 0.f, 0.f};

  uint32 fl = 0;

  for (int k0 = 0; k0 < C_; k0 += 32) {
    #pragma unroll
    for (int i = 0; i < 4; ++i) {
      int c = i * 256 + tid;
      gll16(W0b + (size_t)(c >> 2) * C_ + k0 + (c & 3) * 8, &sm.st.A[c * 8]);
    }
    const float* xr = xbase + (size_t)(k0 + 2 * kp) * N_;
    float4 q0 = *(const float4*)xr;
    float4 q1 = *(const float4*)(xr + N_);
    float a0[4] = {q0.x, q0.y, q0.z, q0.w};
    float a1[4] = {q1.x, q1.y, q1.z, q1.w};
    uint32* bw = (uint32*)sm.st.Bt;
    #pragma unroll
    for (int i = 0; i < 4; ++i) {
      if (a0[i] > 0.f || a1[i] > 0.f) fl |= (1u << i);
      union { bf16 h[2]; uint32 u; } p;
      p.h[0] = (bf16)a0[i];
      p.h[1] = (bf16)a1[i];
      bw[(n4 + i) * 20 + kp] = p.u;
    }
    __syncthreads();

    bf16x8 af[4], bfr[4];
    #pragma unroll
    for (int mt = 0; mt < 4; ++mt)
      af[mt] = *(const bf16x8*)&sm.st.A[(wave * 64 + mt * 16 + l16) * 32 + l4 * 8];
    #pragma unroll
    for (int nt = 0; nt < 4; ++nt)
      bfr[nt] = *(const bf16x8*)&sm.st.Bt[(nt * 16 + l16) * 40 + l4 * 8];
    #pragma unroll
    for (int mt = 0; mt < 4; ++mt)
      #pragma unroll
      for (int nt = 0; nt < 4; ++nt)
        acc[mt][nt] = __builtin_amdgcn_mfma_f32_16x16x32_bf16(af[mt], bfr[nt], acc[mt][nt], 0, 0, 0);
    __syncthreads();
  }

  #pragma unroll
  for (int i = 0; i < 4; ++i)
    if (fl & (1u << i)) atomicOr(&nflag[n4 + i], 1u);
  __syncthreads();
  if (tid < 64) maskb[(size_t)b * N_ + n0 + tid] = nflag[tid] ? 1.f : 0.f;

  #pragma unroll
  for (int mt = 0; mt < 4; ++mt) {
    int m0 = wave * 64 + mt * 16 + l4 * 4;
    #pragma unroll
    for (int nt = 0; nt < 4; ++nt) {
      int n = nt * 16 + l16;
      bf16x4 hv;
      #pragma unroll
      for (int r = 0; r < 4; ++r) {
        float v = acc[mt][nt][r] + sbias[m0 + r];
        v = fminf(fmaxf(v, 0.f), 1.0e4f);
        hv[r] = (bf16)v;
      }
      *(bf16x4*)&sm.HT[n * 264 + m0] = hv;
    }
  }
  __syncthreads();
  {
    int n = tid >> 2, q = tid & 3;
    const char* src = (const char*)&sm.HT[n * 264 + q * 64];
    bf16* dst = h1T + ((size_t)b * N_ + n0 + n) * H_ + q * 64;
    #pragma unroll
    for (int j = 0; j < 8; ++j)
      *(uint4*)((char*)dst + j * 16) = *(const uint4*)(src + j * 16);
  }
}

// -------------------- layers 2/3 -------------------------------------------------
template <int OUTL>
__global__ __launch_bounds__(256) void gemmA(const bf16* __restrict__ A,
                                             const float* __restrict__ bias, int biasLim,
                                             const bf16* __restrict__ Bt,
                                             bf16* __restrict__ outp) {
  __shared__ union {
    struct { bf16 A[256 * 32]; bf16 Bs[64 * 32]; } st;
    bf16 HT[64 * 264];
    bf16 YT[256 * 72];
  } sm;
  __shared__ float sbias[256];

  const int tid  = threadIdx.x;
  const int wave = tid >> 6, lane = tid & 63;
  const int l16  = lane & 15, l4 = lane >> 4;
  const int n0   = blockIdx.x * 64;
  const int mb   = blockIdx.y;
  const int b    = blockIdx.z;
  const int m0g  = mb * 256;

  { int og = m0g + tid; sbias[tid] = (og < biasLim) ? bias[og] : 0.f; }

  floatx4 acc[4][4];
  #pragma unroll
  for (int i = 0; i < 4; ++i)
    #pragma unroll
    for (int j = 0; j < 4; ++j)
      acc[i][j] = floatx4{0.f, 0.f, 0.f, 0.f};

  const bf16* Bbase = Bt + ((size_t)b * N_ + n0) * 256;

  for (int k0 = 0; k0 < 256; k0 += 32) {
    #pragma unroll
    for (int i = 0; i < 4; ++i) {
      int c = i * 256 + tid;
      gll16(A + (size_t)(m0g + (c >> 2)) * 256 + k0 + (c & 3) * 8, &sm.st.A[c * 8]);
    }
    gll16(Bbase + (size_t)(tid >> 2) * 256 + k0 + (tid & 3) * 8, &sm.st.Bs[tid * 8]);
    __syncthreads();

    bf16x8 af[4], bfr[4];
    #pragma unroll
    for (int mt = 0; mt < 4; ++mt)
      af[mt] = *(const bf16x8*)&sm.st.A[(wave * 64 + mt * 16 + l16) * 32 + l4 * 8];
    #pragma unroll
    for (int nt = 0; nt < 4; ++nt)
      bfr[nt] = *(const bf16x8*)&sm.st.Bs[(nt * 16 + l16) * 32 + l4 * 8];
    #pragma unroll
    for (int mt = 0; mt < 4; ++mt)
      #pragma unroll
      for (int nt = 0; nt < 4; ++nt)
        acc[mt][nt] = __builtin_amdgcn_mfma_f32_16x16x32_bf16(af[mt], bfr[nt], acc[mt][nt], 0, 0, 0);
    __syncthreads();
  }

  if constexpr (!OUTL) {
    #pragma unroll
    for (int mt = 0; mt < 4; ++mt) {
      int m0 = wave * 64 + mt * 16 + l4 * 4;
      #pragma unroll
      for (int nt = 0; nt < 4; ++nt) {
        int n = nt * 16 + l16;
        bf16x4 hv;
        #pragma unroll
        for (int r = 0; r < 4; ++r) {
          float v = acc[mt][nt][r] + sbias[m0 + r];
          v = fminf(fmaxf(v, 0.f), 1.0e4f);
          hv[r] = (bf16)v;
        }
        *(bf16x4*)&sm.HT[n * 264 + m0] = hv;
      }
    }
    __syncthreads();
    int n = tid >> 2, q = tid & 3;
    const char* src = (const char*)&sm.HT[n * 264 + q * 64];
    bf16* dst = outp + ((size_t)b * N_ + n0 + n) * H_ + q * 64;
    #pragma unroll
    for (int j = 0; j < 8; ++j)
      *(uint4*)((char*)dst + j * 16) = *(const uint4*)(src + j * 16);
  } else {
    #pragma unroll
    for (int mt = 0; mt < 4; ++mt) {
      int m0 = wave * 64 + mt * 16 + l4 * 4;
      #pragma unroll
      for (int nt = 0; nt < 4; ++nt) {
        int n = nt * 16 + l16;
        #pragma unroll
        for (int r = 0; r < 4; ++r) {
          float v = acc[mt][nt][r] + sbias[m0 + r];
          sm.YT[(m0 + r) * 72 + n] = (bf16)v;
        }
      }
    }
    __syncthreads();
    bf16* dst = outp + ((size_t)b * OP_ + m0g + tid) * N_ + n0;
    const char* src = (const char*)&sm.YT[tid * 72];
    #pragma unroll
    for (int j = 0; j < 8; ++j)
      *(uint4*)((char*)dst + j * 16) = *(const uint4*)(src + j * 16);
  }
}

// -------------------- top-k prefix averaging (16-bit radix select) ---------------
// bf16 y => only 16 significant bits. Monotone key: k = sign? ~b : b|0x8000.
__global__ __launch_bounds__(256) void topk(const bf16* __restrict__ y,
                                            const float* __restrict__ maskb,
                                            float* __restrict__ out) {
  __shared__ uint32 keys[4096];     // 8192 u16 keys packed (8000 real + 192 pad)
  __shared__ uint32 cand[128];
  __shared__ float  sval[128];
  __shared__ float  m100[128];
  __shared__ int    redw[4][3];
  __shared__ int    gcnt;

  const int tid  = threadIdx.x;
  const int wave = tid >> 6, lane = tid & 63;
  const int o = blockIdx.x, b = blockIdx.y;

  const uint32* yw = (const uint32*)(y + ((size_t)b * OP_ + o) * N_);  // 16000B rows: u32-aligned
  const float*  mr = maskb + (size_t)b * N_;

  if (tid < 128) m100[tid] = (tid < 100) ? mr[tid] : 0.f;
  if (tid == 0) gcnt = 0;

  // load + key-convert, packed 2 keys per u32, stride-1 coalesced
  #pragma unroll
  for (int i = 0; i < 16; ++i) {
    int w = i * 256 + tid;          // u32 word index, < 4096
    uint32 kk = 0;                  // pad = minimal keys
    if (w < 4000) {
      uint32 v = yw[w];
      float2 mm = *(const float2*)(mr + 2 * w);
      uint32 b0 = v & 0xffffu, b1 = v >> 16;
      if (mm.x == 0.f) b0 = 0u;     // masked tile -> value +0
      if (mm.y == 0.f) b1 = 0u;
      uint32 k0 = (b0 & 0x8000u) ? (~b0 & 0xffffu) : (b0 | 0x8000u);
      uint32 k1 = (b1 & 0x8000u) ? (~b1 & 0xffffu) : (b1 | 0x8000u);
      kk = k0 | (k1 << 16);
    }
    keys[w] = kk;
  }
  __syncthreads();

  // exact 100th-largest key via 2-bit-per-step radix descent (8 sweeps)
  uint32 prefix = 0;
  for (int shift = 14; shift >= 0; shift -= 2) {
    uint32 t1 = prefix | (1u << shift);
    uint32 t2 = prefix | (2u << shift);
    uint32 t3 = prefix | (3u << shift);
    int c1 = 0, c2 = 0, c3 = 0;
    #pragma unroll
    for (int i = 0; i < 16; ++i) {
      uint32 w = keys[i * 256 + tid];
      uint32 k0 = w & 0xffffu, k1 = w >> 16;
      c1 += (k0 >= t1) + (k1 >= t1);
      c2 += (k0 >= t2) + (k1 >= t2);
      c3 += (k0 >= t3) + (k1 >= t3);
    }
    #pragma unroll
    for (int off = 32; off > 0; off >>= 1) {
      c1 += __shfl_down(c1, off);
      c2 += __shfl_down(c2, off);
      c3 += __shfl_down(c3, off);
    }
    if (lane == 0) { redw[wave][0] = c1; redw[wave][1] = c2; redw[wave][2] = c3; }
    __syncthreads();
    int n1 = redw[0][0] + redw[1][0] + redw[2][0] + redw[3][0];
    int n2 = redw[0][1] + redw[1][1] + redw[2][1] + redw[3][1];
    int n3 = redw[0][2] + redw[1][2] + redw[2][2] + redw[3][2];
    if (n3 >= 100)      prefix = t3;
    else if (n2 >= 100) prefix = t2;
    else if (n1 >= 100) prefix = t1;
    __syncthreads();   // redw reuse guard
  }
  // prefix == T: #{>=T} >= 100, #{>T} <= 99

  // gather strictly-greater, fill ties with T
  #pragma unroll
  for (int i = 0; i < 16; ++i) {
    uint32 w = keys[i * 256 + tid];
    uint32 k0 = w & 0xffffu, k1 = w >> 16;
    if (k0 > prefix) { int p = atomicAdd(&gcnt, 1); cand[p] = k0; }
    if (k1 > prefix) { int p = atomicAdd(&gcnt, 1); cand[p] = k1; }
  }
  __syncthreads();
  int cg = gcnt;                       // <= 99
  if (tid >= cg && tid < 100) cand[tid] = prefix;
  __syncthreads();

  // rank-sort 100 candidates in one pass (broadcast LDS reads)
  if (tid < 100) {
    uint32 ci = cand[tid];
    int rank = 0;
    for (int j = 0; j < 100; ++j) {
      uint32 cj = cand[j];
      rank += (cj > ci) || (cj == ci && j < tid);
    }
    uint32 bb = (ci & 0x8000u) ? (ci & 0x7fffu) : (~ci & 0xffffu);
    sval[rank] = __uint_as_float(bb << 16);
  }
  __syncthreads();

  if (tid == 0) {
    const int KSv[4] = {10, 25, 50, 100};
    float num = 0.f, den = 0.f, pred = 0.f;
    int ki = 0;
    for (int j = 0; j < 100; ++j) {
      num += sval[j] * m100[j];
      den += m100[j];
      if (j + 1 == KSv[ki]) { pred += 0.25f * num / den; ++ki; }
    }
    out[(size_t)b * O_ + o] = pred;
  }
}

// -------------------- launcher ---------------------------------------------------
extern "C" void kernel_launch(void* const* d_in, const int* in_sizes, int n_in,
                              void* d_out, int out_size, void* d_ws, size_t ws_size,
                              hipStream_t stream) {
  const float* x  = (const float*)d_in[0];
  const float* W0 = (const float*)d_in[1];
  const float* b0 = (const float*)d_in[2];
  const float* W1 = (const float*)d_in[3];
  const float* b1 = (const float*)d_in[4];
  const float* W2 = (const float*)d_in[5];
  const float* b2 = (const float*)d_in[6];
  float* out = (float*)d_out;

  char* ws = (char*)d_ws;
  bf16*  W0b  = (bf16*)(ws + 0);
  bf16*  W1b  = (bf16*)(ws + 1048576);
  bf16*  W2b  = (bf16*)(ws + 1179648);
  float* mk   = (float*)(ws + 1703936);
  bf16*  h1T  = (bf16*)(ws + 1959936);
  bf16*  h2T  = (bf16*)(ws + 34727936);
  bf16*  yb   = (bf16*)(ws + 67495936);

  castw<<<3328, 256, 0, stream>>>(W0, W1, W2, W0b, W1b, W2b);
  gemm1<<<dim3(125, 8), 256, 0, stream>>>(x, W0b, b0, h1T, mk);
  gemmA<0><<<dim3(125, 1, 8), 256, 0, stream>>>(W1b, b1, H_, h1T, h2T);
  gemmA<1><<<dim3(125, 4, 8), 256, 0, stream>>>(W2b, b2, O_, h2T, yb);
  topk<<<dim3(1000, 8), 256, 0, stream>>>(yb, mk, out);
}

// Round 3
// 985.720 us; speedup vs baseline: 1.2993x; 1.0230x over previous
//
#include <hip/hip_runtime.h>
#include <hip/hip_bf16.h>
#include <stdint.h>

typedef __bf16 bf16;
typedef __bf16 bf16x8 __attribute__((ext_vector_type(8)));
typedef __bf16 bf16x4 __attribute__((ext_vector_type(4)));
typedef float  floatx4 __attribute__((ext_vector_type(4)));
typedef unsigned int uint32;

#define B_  8
#define C_  2048
#define N_  8000
#define H_  256
#define O_  1000
#define OP_ 1024   // O padded to MFMA-friendly 1024

// async global->LDS, 16B per lane; LDS dst = wave-uniform base + lane*16
__device__ __forceinline__ void gll16(const void* g, void* l) {
  __builtin_amdgcn_global_load_lds((const __attribute__((address_space(1))) void*)g,
                                   (__attribute__((address_space(3))) void*)l, 16, 0, 0);
}

// -------------------- weight pre-cast (fp32 -> bf16, W2 padded to 1024 rows) -----
__global__ __launch_bounds__(256) void castw(const float* __restrict__ W0,
                                             const float* __restrict__ W1,
                                             const float* __restrict__ W2,
                                             bf16* __restrict__ W0b,
                                             bf16* __restrict__ W1b,
                                             bf16* __restrict__ W2b) {
  int idx = blockIdx.x * 256 + threadIdx.x;
  if (idx < 524288) {
    W0b[idx] = (bf16)W0[idx];
  } else if (idx < 524288 + 65536) {
    int i = idx - 524288;
    W1b[i] = (bf16)W1[i];
  } else {
    int i = idx - (524288 + 65536);        // < 1024*256
    int o = i >> 8, k = i & 255;
    W2b[i] = (o < O_) ? (bf16)W2[o * 256 + k] : (bf16)0.0f;
  }
}

// -------------------- layer 1: h1T[b][n][h] = clip(relu(W0 x + b0)) + mask -------
__global__ __launch_bounds__(256) void gemm1(const float* __restrict__ x,
                                             const bf16* __restrict__ W0b,
                                             const float* __restrict__ bias0,
                                             bf16* __restrict__ h1T,
                                             float* __restrict__ maskb) {
  __shared__ union {
    struct { bf16 A[H_ * 32]; bf16 Bt[64 * 40]; } st;
    bf16 HT[64 * 264];
  } sm;
  __shared__ float sbias[256];
  __shared__ uint32 nflag[64];

  const int tid  = threadIdx.x;
  const int wave = tid >> 6, lane = tid & 63;
  const int l16  = lane & 15, l4 = lane >> 4;
  const int n0   = blockIdx.x * 64;
  const int b    = blockIdx.y;

  sbias[tid] = bias0[tid];
  if (tid < 64) nflag[tid] = 0;

  const int kp = tid >> 4;          // 0..15 -> k-pair 2*kp
  const int n4 = (tid & 15) * 4;    // 0..60
  const float* xbase = x + (size_t)b * C_ * N_ + n0 + n4;

  floatx4 acc[4][4];
  #pragma unroll
  for (int i = 0; i < 4; ++i)
    #pragma unroll
    for (int j = 0; j < 4; ++j)
      acc[i][j] = floatx4{0.f, 0.f, 0.f, 0.f};

  uint32 fl = 0;

  for (int k0 = 0; k0 < C_; k0 += 32) {
    #pragma unroll
    for (int i = 0; i < 4; ++i) {
      int c = i * 256 + tid;
      gll16(W0b + (size_t)(c >> 2) * C_ + k0 + (c & 3) * 8, &sm.st.A[c * 8]);
    }
    const float* xr = xbase + (size_t)(k0 + 2 * kp) * N_;
    float4 q0 = *(const float4*)xr;
    float4 q1 = *(const float4*)(xr + N_);
    float a0[4] = {q0.x, q0.y, q0.z, q0.w};
    float a1[4] = {q1.x, q1.y, q1.z, q1.w};
    uint32* bw = (uint32*)sm.st.Bt;
    #pragma unroll
    for (int i = 0; i < 4; ++i) {
      if (a0[i] > 0.f || a1[i] > 0.f) fl |= (1u << i);
      union { bf16 h[2]; uint32 u; } p;
      p.h[0] = (bf16)a0[i];
      p.h[1] = (bf16)a1[i];
      bw[(n4 + i) * 20 + kp] = p.u;
    }
    __syncthreads();

    bf16x8 af[4], bfr[4];
    #pragma unroll
    for (int mt = 0; mt < 4; ++mt)
      af[mt] = *(const bf16x8*)&sm.st.A[(wave * 64 + mt * 16 + l16) * 32 + l4 * 8];
    #pragma unroll
    for (int nt = 0; nt < 4; ++nt)
      bfr[nt] = *(const bf16x8*)&sm.st.Bt[(nt * 16 + l16) * 40 + l4 * 8];
    #pragma unroll
    for (int mt = 0; mt < 4; ++mt)
      #pragma unroll
      for (int nt = 0; nt < 4; ++nt)
        acc[mt][nt] = __builtin_amdgcn_mfma_f32_16x16x32_bf16(af[mt], bfr[nt], acc[mt][nt], 0, 0, 0);
    __syncthreads();
  }

  #pragma unroll
  for (int i = 0; i < 4; ++i)
    if (fl & (1u << i)) atomicOr(&nflag[n4 + i], 1u);
  __syncthreads();
  if (tid < 64) maskb[(size_t)b * N_ + n0 + tid] = nflag[tid] ? 1.f : 0.f;

  #pragma unroll
  for (int mt = 0; mt < 4; ++mt) {
    int m0 = wave * 64 + mt * 16 + l4 * 4;
    #pragma unroll
    for (int nt = 0; nt < 4; ++nt) {
      int n = nt * 16 + l16;
      bf16x4 hv;
      #pragma unroll
      for (int r = 0; r < 4; ++r) {
        float v = acc[mt][nt][r] + sbias[m0 + r];
        v = fminf(fmaxf(v, 0.f), 1.0e4f);
        hv[r] = (bf16)v;
      }
      *(bf16x4*)&sm.HT[n * 264 + m0] = hv;
    }
  }
  __syncthreads();
  {
    int n = tid >> 2, q = tid & 3;
    const char* src = (const char*)&sm.HT[n * 264 + q * 64];
    bf16* dst = h1T + ((size_t)b * N_ + n0 + n) * H_ + q * 64;
    #pragma unroll
    for (int j = 0; j < 8; ++j)
      *(uint4*)((char*)dst + j * 16) = *(const uint4*)(src + j * 16);
  }
}

// -------------------- layers 2/3 -------------------------------------------------
// OUTL=1 additionally multiplies the padding mask into y (so topk needs no mask).
template <int OUTL>
__global__ __launch_bounds__(256) void gemmA(const bf16* __restrict__ A,
                                             const float* __restrict__ bias, int biasLim,
                                             const bf16* __restrict__ Bt,
                                             const float* __restrict__ mk,
                                             bf16* __restrict__ outp) {
  __shared__ union {
    struct { bf16 A[256 * 32]; bf16 Bs[64 * 32]; } st;
    bf16 HT[64 * 264];
    bf16 YT[256 * 72];
  } sm;
  __shared__ float sbias[256];
  __shared__ float smk[64];

  const int tid  = threadIdx.x;
  const int wave = tid >> 6, lane = tid & 63;
  const int l16  = lane & 15, l4 = lane >> 4;
  const int n0   = blockIdx.x * 64;
  const int mb   = blockIdx.y;
  const int b    = blockIdx.z;
  const int m0g  = mb * 256;

  { int og = m0g + tid; sbias[tid] = (og < biasLim) ? bias[og] : 0.f; }
  if (OUTL && tid < 64) smk[tid] = mk[(size_t)b * N_ + n0 + tid];

  floatx4 acc[4][4];
  #pragma unroll
  for (int i = 0; i < 4; ++i)
    #pragma unroll
    for (int j = 0; j < 4; ++j)
      acc[i][j] = floatx4{0.f, 0.f, 0.f, 0.f};

  const bf16* Bbase = Bt + ((size_t)b * N_ + n0) * 256;

  for (int k0 = 0; k0 < 256; k0 += 32) {
    #pragma unroll
    for (int i = 0; i < 4; ++i) {
      int c = i * 256 + tid;
      gll16(A + (size_t)(m0g + (c >> 2)) * 256 + k0 + (c & 3) * 8, &sm.st.A[c * 8]);
    }
    gll16(Bbase + (size_t)(tid >> 2) * 256 + k0 + (tid & 3) * 8, &sm.st.Bs[tid * 8]);
    __syncthreads();

    bf16x8 af[4], bfr[4];
    #pragma unroll
    for (int mt = 0; mt < 4; ++mt)
      af[mt] = *(const bf16x8*)&sm.st.A[(wave * 64 + mt * 16 + l16) * 32 + l4 * 8];
    #pragma unroll
    for (int nt = 0; nt < 4; ++nt)
      bfr[nt] = *(const bf16x8*)&sm.st.Bs[(nt * 16 + l16) * 32 + l4 * 8];
    #pragma unroll
    for (int mt = 0; mt < 4; ++mt)
      #pragma unroll
      for (int nt = 0; nt < 4; ++nt)
        acc[mt][nt] = __builtin_amdgcn_mfma_f32_16x16x32_bf16(af[mt], bfr[nt], acc[mt][nt], 0, 0, 0);
    __syncthreads();
  }

  if constexpr (!OUTL) {
    #pragma unroll
    for (int mt = 0; mt < 4; ++mt) {
      int m0 = wave * 64 + mt * 16 + l4 * 4;
      #pragma unroll
      for (int nt = 0; nt < 4; ++nt) {
        int n = nt * 16 + l16;
        bf16x4 hv;
        #pragma unroll
        for (int r = 0; r < 4; ++r) {
          float v = acc[mt][nt][r] + sbias[m0 + r];
          v = fminf(fmaxf(v, 0.f), 1.0e4f);
          hv[r] = (bf16)v;
        }
        *(bf16x4*)&sm.HT[n * 264 + m0] = hv;
      }
    }
    __syncthreads();
    int n = tid >> 2, q = tid & 3;
    const char* src = (const char*)&sm.HT[n * 264 + q * 64];
    bf16* dst = outp + ((size_t)b * N_ + n0 + n) * H_ + q * 64;
    #pragma unroll
    for (int j = 0; j < 8; ++j)
      *(uint4*)((char*)dst + j * 16) = *(const uint4*)(src + j * 16);
  } else {
    #pragma unroll
    for (int mt = 0; mt < 4; ++mt) {
      int m0 = wave * 64 + mt * 16 + l4 * 4;
      #pragma unroll
      for (int nt = 0; nt < 4; ++nt) {
        int n = nt * 16 + l16;
        float m = smk[n];
        #pragma unroll
        for (int r = 0; r < 4; ++r) {
          float v = (acc[mt][nt][r] + sbias[m0 + r]) * m;   // fused padding mask
          sm.YT[(m0 + r) * 72 + n] = (bf16)v;
        }
      }
    }
    __syncthreads();
    bf16* dst = outp + ((size_t)b * OP_ + m0g + tid) * N_ + n0;
    const char* src = (const char*)&sm.YT[tid * 72];
    #pragma unroll
    for (int j = 0; j < 8; ++j)
      *(uint4*)((char*)dst + j * 16) = *(const uint4*)(src + j * 16);
  }
}

// -------------------- top-k prefix averaging -------------------------------------
// One wave per (b,o). y is pre-masked. 8000 bf16 -> 4000 u32 words -> monotone u16
// key pairs held in 128 VGPRs (khi = packed pair, klo = pair<<16). 1-bit radix
// descent: each reg needs ONE u32 compare vs uniform (prefix|bit)<<16 per sweep.
// Count via shfl_xor butterfly. Single wave => no s_barrier at all.
__global__ __launch_bounds__(64) void topk(const bf16* __restrict__ y,
                                           const float* __restrict__ maskb,
                                           float* __restrict__ out) {
  __shared__ uint32 cand[128];
  __shared__ float  sval[128];
  __shared__ float  m100[100];
  __shared__ int    gcnt;

  const int lane = threadIdx.x;
  const int o = blockIdx.x, b = blockIdx.y;

  const uint32* yw = (const uint32*)(y + ((size_t)b * OP_ + o) * N_);  // 16000B rows
  const float*  mr = maskb + (size_t)b * N_;

  if (lane == 0) gcnt = 0;
  m100[lane] = mr[lane];
  if (lane < 36) m100[64 + lane] = mr[64 + lane];

  uint32 khi[64], klo[64];
  #pragma unroll
  for (int i = 0; i < 16; ++i) {
    int base = i * 256 + lane * 4;          // word index; lanes>=40 at i=15 are pad
    bool real = (base < 4000);
    uint4 v = make_uint4(0u, 0u, 0u, 0u);
    if (real) v = *(const uint4*)(yw + base);
    uint32 ww[4] = {v.x, v.y, v.z, v.w};
    #pragma unroll
    for (int j = 0; j < 4; ++j) {
      uint32 w = ww[j];
      uint32 sgn = w & 0x80008000u;
      uint32 mskk = 0x80008000u | (sgn - (sgn >> 15));  // per-half: neg?0xffff:0x8000
      uint32 k = w ^ mskk;                               // packed monotone keys
      if (!real) k = 0u;                                 // pad = strict minimum
      khi[i * 4 + j] = k;
      klo[i * 4 + j] = k << 16;
    }
  }

  // 16-sweep 1-bit radix descent for the exact 100th-largest key
  uint32 prefix = 0;
  #pragma unroll 1
  for (int bit = 15; bit >= 0; --bit) {
    uint32 T16 = (prefix | (1u << bit)) << 16;
    int c = 0, d = 0;
    #pragma unroll
    for (int r = 0; r < 64; ++r) {
      c += (khi[r] >= T16);   // w >= t<<16  <=>  hi-key >= t
      d += (klo[r] >= T16);   // (lo<<16) >= t<<16  <=>  lo-key >= t
    }
    c += d;
    #pragma unroll
    for (int m = 1; m < 64; m <<= 1) c += __shfl_xor(c, m, 64);
    if (c >= 100) prefix |= (1u << bit);
  }
  // prefix == T: #{>=T} >= 100, #{>T} <= 99

  // gather strictly-greater keys (<=99), fill ties with T
  #pragma unroll
  for (int r = 0; r < 64; ++r) {
    uint32 h = khi[r] >> 16;
    uint32 l = khi[r] & 0xffffu;
    if (h > prefix) { int p = atomicAdd(&gcnt, 1); cand[p] = h; }
    if (l > prefix) { int p = atomicAdd(&gcnt, 1); cand[p] = l; }
  }
  __syncthreads();
  int cg = gcnt;
  for (int idx = lane; idx < 100; idx += 64)
    if (idx >= cg) cand[idx] = prefix;
  __syncthreads();

  // rank-sort 100 keys (broadcast LDS reads), convert key -> fp32 value
  for (int idx = lane; idx < 100; idx += 64) {
    uint32 ci = cand[idx];
    int rank = 0;
    for (int j = 0; j < 100; ++j) {
      uint32 cj = cand[j];
      rank += (cj > ci) || (cj == ci && j < idx);
    }
    uint32 bb = (ci & 0x8000u) ? (ci & 0x7fffu) : (~ci & 0xffffu);
    sval[rank] = __uint_as_float(bb << 16);
  }
  __syncthreads();

  if (lane == 0) {
    const int KSv[4] = {10, 25, 50, 100};
    float num = 0.f, den = 0.f, pred = 0.f;
    int ki = 0;
    for (int j = 0; j < 100; ++j) {
      num += sval[j] * m100[j];
      den += m100[j];
      if (j + 1 == KSv[ki]) { pred += 0.25f * num / den; ++ki; }
    }
    out[(size_t)b * O_ + o] = pred;
  }
}

// -------------------- launcher ---------------------------------------------------
extern "C" void kernel_launch(void* const* d_in, const int* in_sizes, int n_in,
                              void* d_out, int out_size, void* d_ws, size_t ws_size,
                              hipStream_t stream) {
  const float* x  = (const float*)d_in[0];
  const float* W0 = (const float*)d_in[1];
  const float* b0 = (const float*)d_in[2];
  const float* W1 = (const float*)d_in[3];
  const float* b1 = (const float*)d_in[4];
  const float* W2 = (const float*)d_in[5];
  const float* b2 = (const float*)d_in[6];
  float* out = (float*)d_out;

  char* ws = (char*)d_ws;
  bf16*  W0b  = (bf16*)(ws + 0);
  bf16*  W1b  = (bf16*)(ws + 1048576);
  bf16*  W2b  = (bf16*)(ws + 1179648);
  float* mk   = (float*)(ws + 1703936);
  bf16*  h1T  = (bf16*)(ws + 1959936);
  bf16*  h2T  = (bf16*)(ws + 34727936);
  bf16*  yb   = (bf16*)(ws + 67495936);

  castw<<<3328, 256, 0, stream>>>(W0, W1, W2, W0b, W1b, W2b);
  gemm1<<<dim3(125, 8), 256, 0, stream>>>(x, W0b, b0, h1T, mk);
  gemmA<0><<<dim3(125, 1, 8), 256, 0, stream>>>(W1b, b1, H_, h1T, nullptr, h2T);
  gemmA<1><<<dim3(125, 4, 8), 256, 0, stream>>>(W2b, b2, O_, h2T, mk, yb);
  topk<<<dim3(1000, 8), 64, 0, stream>>>(yb, mk, out);
}